// Round 6
// baseline (471.936 us; speedup 1.0000x reference)
//
#include <hip/hip_runtime.h>

#define DECAYF 0.99f
#define ONEMF 0.01f
#define EPSF 1e-5f

typedef __bf16 bf16x8 __attribute__((ext_vector_type(8)));
typedef float f32x4 __attribute__((ext_vector_type(4)));
typedef unsigned short ushort8 __attribute__((ext_vector_type(8)));

// ws layout (float indices):
// [0,65536)        dw accumulator (K*D)
// [65536,66560)    counts (K)
// [66560,67584)    nchalf = -0.5*||e_k||^2
// [67584]          sse
// [67600,100368)   E_hi as bf16 (ushort), row-major [K][D]
// [100368,133136)  E_lo as bf16 (ushort)
// [133136,198672)  idx per token (int)
// [198672,4392976) xT: x transposed to [token][64] (atomic-free path only)
#define WS_COUNTS 65536
#define WS_NCHALF 66560
#define WS_SSE    67584
#define WS_EHI    67600
#define WS_ELO    100368
#define WS_IDX    133136
#define WS_XT     198672
#define WS_NEED_BYTES ((size_t)(WS_XT + 4194304) * 4)

__device__ __forceinline__ float wave_reduce_add(float v) {
#pragma unroll
    for (int o = 32; o > 0; o >>= 1) v += __shfl_xor(v, o, 64);
    return v;
}

__device__ __forceinline__ unsigned short bf_rne(float f) {
    unsigned int u = __float_as_uint(f);
    unsigned int r = u + 0x7fffu + ((u >> 16) & 1u);
    return (unsigned short)(r >> 16);
}

// Zero dw/counts/sse; split E into bf16 hi/lo; nchalf. grid 256 x 256.
__global__ __launch_bounds__(256) void prep_kernel(const float* __restrict__ E,
                                                   float* __restrict__ ws) {
    const int bid = blockIdx.x, tid = threadIdx.x;
    const int id = bid * 256 + tid;            // element of E (k = id>>6, c = id&63)
    ws[id] = 0.0f;                             // dw (needed by atomic fallback only)
    if (bid < 4) ws[WS_COUNTS + bid * 256 + tid] = 0.0f;
    if (bid == 4 && tid == 0) ws[WS_SSE] = 0.0f;
    const float v = E[id];
    const unsigned short h = bf_rne(v);
    const float hf = __uint_as_float((unsigned int)h << 16);
    const unsigned short l = bf_rne(v - hf);
    ((unsigned short*)(ws + WS_EHI))[id] = h;
    ((unsigned short*)(ws + WS_ELO))[id] = l;
    const int lane = tid & 63;
    const float s = wave_reduce_add(v * v);
    if (lane == 0) ws[WS_NCHALF + (id >> 6)] = -0.5f * s;
}

// Scoring: MFMA scores + top-2 + fp64 re-rank. Writes idx[] + sse ONLY (no atomScatter).
// grid 512 x 256; each block = 128 tokens.
__global__ __launch_bounds__(256) void vq_score(const float* __restrict__ x,
                                                const float* __restrict__ E,
                                                float* __restrict__ ws) {
    const int tid = threadIdx.x;
    const int lane = tid & 63;
    const int w = tid >> 6;
    const int blk = blockIdx.x;
    const int b = blk >> 5;            // batch
    const int hw0 = (blk & 31) << 7;   // hw offset (128 tokens)
    const int tok0 = blk << 7;

    __shared__ float xs[128 * 68];
    __shared__ int i1sh[128], i2sh[128];

    // Stage x tile (fully coalesced).
    {
        const float* xb = x + ((size_t)b << 18) + hw0;
#pragma unroll
        for (int cc = 0; cc < 32; ++cc) {
            const int id = cc * 256 + tid;
            const int c = id >> 7, t = id & 127;
            xs[t * 68 + c] = xb[((size_t)c << 12) + t];
        }
    }
    __syncthreads();

    const int q = lane >> 4, m = lane & 15;

    bf16x8 Ah[2][2], Al[2][2];
#pragma unroll
    for (int t = 0; t < 2; ++t) {
        const int tok = w * 32 + t * 16 + m;
#pragma unroll
        for (int s = 0; s < 2; ++s) {
            const float* p = &xs[tok * 68 + s * 32 + q * 8];
            ushort8 hu, lu;
#pragma unroll
            for (int j = 0; j < 8; ++j) {
                const float f = p[j];
                const unsigned short h = bf_rne(f);
                const float hf = __uint_as_float((unsigned int)h << 16);
                hu[j] = h;
                lu[j] = bf_rne(f - hf);
            }
            Ah[t][s] = __builtin_bit_cast(bf16x8, hu);
            Al[t][s] = __builtin_bit_cast(bf16x8, lu);
        }
    }

    const ushort8* __restrict__ Ehp = (const ushort8*)(ws + WS_EHI);
    const ushort8* __restrict__ Elp = (const ushort8*)(ws + WS_ELO);
    const float* __restrict__ ncp = ws + WS_NCHALF;

    float b1[2][4], b2[2][4];
    int i1[2][4], i2[2][4];
#pragma unroll
    for (int t = 0; t < 2; ++t)
#pragma unroll
        for (int r = 0; r < 4; ++r) { b1[t][r] = -1e30f; b2[t][r] = -1e30f; i1[t][r] = 0; i2[t][r] = 1; }

    ushort8 p0h[2], p1h[2], p0l[2], p1l[2];
    float pnc[2];
#pragma unroll
    for (int s = 0; s < 2; ++s) {
        const int code = s * 16 + m;
        p0h[s] = Ehp[code * 8 + q];
        p1h[s] = Ehp[code * 8 + 4 + q];
        p0l[s] = Elp[code * 8 + q];
        p1l[s] = Elp[code * 8 + 4 + q];
        pnc[s] = ncp[code];
    }

#define VQ_STEP(S, CK)                                                          \
    {                                                                           \
        const bf16x8 bh0 = __builtin_bit_cast(bf16x8, p0h[S]);                  \
        const bf16x8 bh1 = __builtin_bit_cast(bf16x8, p1h[S]);                  \
        const bf16x8 bl0 = __builtin_bit_cast(bf16x8, p0l[S]);                  \
        const bf16x8 bl1 = __builtin_bit_cast(bf16x8, p1l[S]);                  \
        const float nc = pnc[S];                                                \
        if ((CK) + 2 < 64) {                                                    \
            const int code = ((CK) + 2) * 16 + m;                               \
            p0h[S] = Ehp[code * 8 + q];                                         \
            p1h[S] = Ehp[code * 8 + 4 + q];                                     \
            p0l[S] = Elp[code * 8 + q];                                         \
            p1l[S] = Elp[code * 8 + 4 + q];                                     \
            pnc[S] = ncp[code];                                                 \
        }                                                                       \
        const int idx = (CK) * 16 + m;                                          \
        _Pragma("unroll")                                                       \
        for (int t = 0; t < 2; ++t) {                                           \
            f32x4 acc = {nc, nc, nc, nc}; /* score = x.e - 0.5||e||^2 */        \
            acc = __builtin_amdgcn_mfma_f32_16x16x32_bf16(Ah[t][0], bh0, acc, 0, 0, 0); \
            acc = __builtin_amdgcn_mfma_f32_16x16x32_bf16(Ah[t][1], bh1, acc, 0, 0, 0); \
            acc = __builtin_amdgcn_mfma_f32_16x16x32_bf16(Al[t][0], bh0, acc, 0, 0, 0); \
            acc = __builtin_amdgcn_mfma_f32_16x16x32_bf16(Al[t][1], bh1, acc, 0, 0, 0); \
            acc = __builtin_amdgcn_mfma_f32_16x16x32_bf16(Ah[t][0], bl0, acc, 0, 0, 0); \
            acc = __builtin_amdgcn_mfma_f32_16x16x32_bf16(Ah[t][1], bl1, acc, 0, 0, 0); \
            _Pragma("unroll")                                                   \
            for (int r = 0; r < 4; ++r) {                                       \
                const float s = acc[r];                                         \
                const bool cA = s > b1[t][r];                                   \
                const bool cB = s > b2[t][r];                                   \
                b2[t][r] = cA ? b1[t][r] : (cB ? s : b2[t][r]);                 \
                i2[t][r] = cA ? i1[t][r] : (cB ? idx : i2[t][r]);               \
                b1[t][r] = cA ? s : b1[t][r];                                   \
                i1[t][r] = cA ? idx : i1[t][r];                                 \
            }                                                                   \
        }                                                                       \
    }

    for (int j = 0; j < 32; ++j) {
        VQ_STEP(0, 2 * j)
        VQ_STEP(1, 2 * j + 1)
    }
#undef VQ_STEP

#pragma unroll
    for (int d = 1; d < 16; d <<= 1) {
#pragma unroll
        for (int t = 0; t < 2; ++t)
#pragma unroll
            for (int r = 0; r < 4; ++r) {
                const float ob1 = __shfl_xor(b1[t][r], d, 64);
                const int   oi1 = __shfl_xor(i1[t][r], d, 64);
                const float ob2 = __shfl_xor(b2[t][r], d, 64);
                const int   oi2 = __shfl_xor(i2[t][r], d, 64);
                const bool wv = ob1 > b1[t][r];
                const float t1 = wv ? ob1 : b1[t][r]; const int ti1 = wv ? oi1 : i1[t][r];
                const float sA = wv ? b1[t][r] : ob1; const int siA = wv ? i1[t][r] : oi1;
                const float sB = wv ? ob2 : b2[t][r]; const int siB = wv ? oi2 : i2[t][r];
                const bool w2 = sB > sA;
                b1[t][r] = t1; i1[t][r] = ti1;
                b2[t][r] = w2 ? sB : sA; i2[t][r] = w2 ? siB : siA;
            }
    }
    if (m == 0) {
#pragma unroll
        for (int t = 0; t < 2; ++t)
#pragma unroll
            for (int r = 0; r < 4; ++r) {
                const int tokL = w * 32 + t * 16 + q * 4 + r;
                i1sh[tokL] = i1[t][r];
                i2sh[tokL] = i2[t][r];
            }
    }

    // fp64 re-rank (same wave -> no barrier needed).
    float dval = 0.0f;
    if (lane < 32) {
        const int tokL = w * 32 + lane;
        const int I1 = i1sh[tokL], I2 = i2sh[tokL];
        const int ca = I1 < I2 ? I1 : I2;
        const int cb = I1 < I2 ? I2 : I1;
        const float* Ea = E + ca * 64;
        const float* Eb = E + cb * 64;
        const float* xr = &xs[tokL * 68];
        double sa = 0, ea = 0, sb = 0, eb = 0, x2 = 0;
#pragma unroll 8
        for (int c = 0; c < 64; ++c) {
            const double xv = (double)xr[c];
            const double va = (double)Ea[c], vb = (double)Eb[c];
            sa += xv * va; ea += va * va;
            sb += xv * vb; eb += vb * vb;
            x2 += xv * xv;
        }
        const double qa = ea - 2.0 * sa;
        const double qb = eb - 2.0 * sb;
        int best; double qq;
        if (qb < qa) { best = cb; qq = qb; } else { best = ca; qq = qa; }
        ((int*)(ws + WS_IDX))[tok0 + tokL] = best;
        float dd = (float)(qq + x2);
        dval = dd < 0.f ? 0.f : dd;
    }
    const float ssum = wave_reduce_add(dval);
    if (lane == 0) atomicAdd(&ws[WS_SSE], ssum);
}

// Output streaming (atomic-free path): q_st + one-hot enc rows + xT copy. NO atomics.
// grid 2048 x 256; each block = 32 tokens.
__global__ __launch_bounds__(256) void vq_out_clean(const float* __restrict__ x,
                                                    const float* __restrict__ E,
                                                    float* __restrict__ out,
                                                    float* __restrict__ ws) {
    const int tid = threadIdx.x;
    const int lane = tid & 63;
    const int w = tid >> 6;
    const int blk = blockIdx.x;
    const int b = blk >> 7;
    const int hw0 = (blk & 127) << 5;
    const int tok0 = blk << 5;

    __shared__ float xsb[32 * 65];
    __shared__ float eqb[32 * 65];
    __shared__ int idxb[32];

    if (tid < 32) idxb[tid] = ((const int*)(ws + WS_IDX))[tok0 + tid];
    {
        const float* xb = x + ((size_t)b << 18) + hw0;
#pragma unroll
        for (int cc = 0; cc < 8; ++cc) {
            const int id = cc * 256 + tid;
            const int t = id & 31, c = id >> 5;
            xsb[t * 65 + c] = xb[((size_t)c << 12) + t];
        }
    }
    __syncthreads();
#pragma unroll
    for (int j = 0; j < 8; ++j) {
        const int t = w * 8 + j;
        eqb[t * 65 + lane] = E[idxb[t] * 64 + lane];
    }
    // xT copy for vq_dw (coalesced 256B rows).
    {
        float* xt = ws + WS_XT;
#pragma unroll
        for (int cc = 0; cc < 8; ++cc) {
            const int id = cc * 256 + tid;
            const int t = id >> 6, c = id & 63;
            xt[(size_t)(tok0 + t) * 64 + c] = xsb[t * 65 + c];
        }
    }
    __syncthreads();

    float* outq = out + 1;
#pragma unroll
    for (int cc = 0; cc < 8; ++cc) {
        const int c = cc * 8 + (tid >> 5);
        const int t = tid & 31;
        const float xv = xsb[t * 65 + c];
        const float eq = eqb[t * 65 + c];
        outq[((size_t)(b * 64 + c) << 12) + hw0 + t] = xv + (eq - xv);
    }

    {
        float* enc = out + 1 + (size_t)4194304;
        const int c0 = tid << 2;
        for (int t = 0; t < 32; ++t) {
            const int kb = idxb[t];
            f32x4 v;
            v[0] = (c0 == kb) ? 1.0f : 0.0f;
            v[1] = (c0 + 1 == kb) ? 1.0f : 0.0f;
            v[2] = (c0 + 2 == kb) ? 1.0f : 0.0f;
            v[3] = (c0 + 3 == kb) ? 1.0f : 0.0f;
            __builtin_nontemporal_store(v, (f32x4*)(enc + (size_t)(tok0 + t) * 1024 + c0));
        }
    }
}

// dw + counts via ballot-scan, NO atomics. grid 256 x 1024; block owns codes [bid*4, bid*4+4).
// Each wave scans a disjoint 4096-token slice; register accumulation; LDS reduce.
__global__ __launch_bounds__(1024) void vq_dw(float* __restrict__ ws) {
    const int tid = threadIdx.x;
    const int wv = tid >> 6;          // 0..15
    const int lane = tid & 63;
    const int k0 = blockIdx.x * 4;
    const int* __restrict__ idxp = (const int*)(ws + WS_IDX);
    const float* __restrict__ xt = ws + WS_XT;

    float a0 = 0.f, a1 = 0.f, a2 = 0.f, a3 = 0.f;
    int c0 = 0, c1 = 0, c2 = 0, c3 = 0;
    const int tbase = wv << 12;       // 4096 tokens per wave

    for (int it = 0; it < 64; ++it) {
        const int trow = tbase + (it << 6);
        const int v = idxp[trow + lane];
        unsigned long long m0 = __ballot(v == k0);
        unsigned long long m1 = __ballot(v == k0 + 1);
        unsigned long long m2 = __ballot(v == k0 + 2);
        unsigned long long m3 = __ballot(v == k0 + 3);
        c0 += __popcll(m0); c1 += __popcll(m1);
        c2 += __popcll(m2); c3 += __popcll(m3);
        while (m0) { const int bít = __builtin_ctzll(m0); m0 &= m0 - 1;
                     a0 += xt[(size_t)(trow + bít) * 64 + lane]; }
        while (m1) { const int bít = __builtin_ctzll(m1); m1 &= m1 - 1;
                     a1 += xt[(size_t)(trow + bít) * 64 + lane]; }
        while (m2) { const int bít = __builtin_ctzll(m2); m2 &= m2 - 1;
                     a2 += xt[(size_t)(trow + bít) * 64 + lane]; }
        while (m3) { const int bít = __builtin_ctzll(m3); m3 &= m3 - 1;
                     a3 += xt[(size_t)(trow + bít) * 64 + lane]; }
    }

    __shared__ float red[16][4][64];
    __shared__ int redc[16][4];
    red[wv][0][lane] = a0; red[wv][1][lane] = a1;
    red[wv][2][lane] = a2; red[wv][3][lane] = a3;
    if (lane == 0) { redc[wv][0] = c0; redc[wv][1] = c1; redc[wv][2] = c2; redc[wv][3] = c3; }
    __syncthreads();
    if (tid < 256) {
        const int c = tid >> 6, l = tid & 63;
        float s = 0.f;
#pragma unroll
        for (int i = 0; i < 16; ++i) s += red[i][c][l];
        ws[(k0 + c) * 64 + l] = s;                    // dw written densely
    }
    if (tid < 4) {
        int s = 0;
#pragma unroll
        for (int i = 0; i < 16; ++i) s += redc[i][tid];
        ws[WS_COUNTS + k0 + tid] = (float)s;          // counts written densely
    }
}

// ---- Fallback path (ws too small for xT): R5-style streaming + atomics ----
__global__ __launch_bounds__(256) void vq_out_atomic(const float* __restrict__ x,
                                                     const float* __restrict__ E,
                                                     float* __restrict__ out,
                                                     float* __restrict__ ws) {
    const int tid = threadIdx.x;
    const int lane = tid & 63;
    const int w = tid >> 6;
    const int blk = blockIdx.x;
    const int b = blk >> 7;
    const int hw0 = (blk & 127) << 5;
    const int tok0 = blk << 5;

    __shared__ float xsb[32 * 65];
    __shared__ float eqb[32 * 65];
    __shared__ int idxb[32];

    if (tid < 32) idxb[tid] = ((const int*)(ws + WS_IDX))[tok0 + tid];
    {
        const float* xb = x + ((size_t)b << 18) + hw0;
#pragma unroll
        for (int cc = 0; cc < 8; ++cc) {
            const int id = cc * 256 + tid;
            const int t = id & 31, c = id >> 5;
            xsb[t * 65 + c] = xb[((size_t)c << 12) + t];
        }
    }
    __syncthreads();
#pragma unroll
    for (int j = 0; j < 8; ++j) {
        const int t = w * 8 + j;
        eqb[t * 65 + lane] = E[idxb[t] * 64 + lane];
    }
    __syncthreads();

    float* outq = out + 1;
#pragma unroll
    for (int cc = 0; cc < 8; ++cc) {
        const int c = cc * 8 + (tid >> 5);
        const int t = tid & 31;
        const float xv = xsb[t * 65 + c];
        const float eq = eqb[t * 65 + c];
        outq[((size_t)(b * 64 + c) << 12) + hw0 + t] = xv + (eq - xv);
    }
    {
        float* enc = out + 1 + (size_t)4194304;
        const int c0 = tid << 2;
        for (int t = 0; t < 32; ++t) {
            const int kb = idxb[t];
            f32x4 v;
            v[0] = (c0 == kb) ? 1.0f : 0.0f;
            v[1] = (c0 + 1 == kb) ? 1.0f : 0.0f;
            v[2] = (c0 + 2 == kb) ? 1.0f : 0.0f;
            v[3] = (c0 + 3 == kb) ? 1.0f : 0.0f;
            __builtin_nontemporal_store(v, (f32x4*)(enc + (size_t)(tok0 + t) * 1024 + c0));
        }
    }
#pragma unroll
    for (int j = 0; j < 8; ++j) {
        const int t = w * 8 + j;
        const int kb = idxb[t];
        atomicAdd(&ws[kb * 64 + lane], xsb[t * 65 + lane]);
        if (lane == 0) atomicAdd(&ws[WS_COUNTS + kb], 1.0f);
    }
}

// new_cs (Laplace-smoothed) + loss. 1 block x 1024.
__global__ __launch_bounds__(1024) void fin_cs(const float* __restrict__ cs_in,
                                               float* __restrict__ out,
                                               const float* __restrict__ ws) {
    __shared__ float red[16];
    __shared__ float n_sh;
    const int tid = threadIdx.x;
    const float raw = cs_in[tid] * DECAYF + ONEMF * ws[WS_COUNTS + tid];
    const float s = wave_reduce_add(raw);
    if ((tid & 63) == 0) red[tid >> 6] = s;
    __syncthreads();
    if (tid == 0) {
        float n = 0.f;
#pragma unroll
        for (int i = 0; i < 16; ++i) n += red[i];
        n_sh = n;
        out[0] = 0.25f * ws[WS_SSE] * (1.0f / 4194304.0f);  // loss
    }
    __syncthreads();
    const float n = n_sh;
    out[71368705 + tid] = (raw + EPSF) / (n + 1024.0f * EPSF) * n;
}

// new_ema_weight and new_embedding. grid 256 x 256.
__global__ __launch_bounds__(256) void fin_w(const float* __restrict__ emaw,
                                             float* __restrict__ out,
                                             const float* __restrict__ ws) {
    const int i = blockIdx.x * 256 + threadIdx.x;
    const float val = emaw[i] * DECAYF + ONEMF * ws[i];
    out[71369729 + i] = val;                               // new_ema_weight
    const float cs = out[71368705 + (i >> 6)];             // new_cs (from fin_cs)
    out[71303169 + i] = val / cs;                          // new_embedding
}

extern "C" void kernel_launch(void* const* d_in, const int* in_sizes, int n_in,
                              void* d_out, int out_size, void* d_ws, size_t ws_size,
                              hipStream_t stream) {
    const float* x    = (const float*)d_in[0];   // [16,64,64,64]
    const float* E    = (const float*)d_in[1];   // [1024,64]
    const float* cs   = (const float*)d_in[2];   // [1024]
    const float* emaw = (const float*)d_in[3];   // [1024,64]
    float* out = (float*)d_out;
    float* ws  = (float*)d_ws;

    prep_kernel<<<256, 256, 0, stream>>>(E, ws);
    vq_score<<<512, 256, 0, stream>>>(x, E, ws);
    if (ws_size >= WS_NEED_BYTES) {
        vq_out_clean<<<2048, 256, 0, stream>>>(x, E, out, ws);
        vq_dw<<<256, 1024, 0, stream>>>(ws);
    } else {
        vq_out_atomic<<<2048, 256, 0, stream>>>(x, E, out, ws);
    }
    fin_cs<<<1, 1024, 0, stream>>>(cs, out, ws);
    fin_w<<<256, 256, 0, stream>>>(emaw, out, ws);
}

// Round 7
// 381.378 us; speedup vs baseline: 1.2374x; 1.2374x over previous
//
#include <hip/hip_runtime.h>

#define DECAYF 0.99f
#define ONEMF 0.01f
#define EPSF 1e-5f

typedef __bf16 bf16x8 __attribute__((ext_vector_type(8)));
typedef float f32x4 __attribute__((ext_vector_type(4)));
typedef unsigned short ushort8 __attribute__((ext_vector_type(8)));

// ws layout (float indices):
// [0,65536)        dw accumulator (K*D)
// [65536,66560)    counts (K)
// [66560,67584)    nchalf = -0.5*||e_k||^2
// [67584]          sse
// [67600,100368)   E_hi as bf16 (ushort), row-major [K][D]
// [100368,133136)  E_lo as bf16 (ushort)
#define WS_COUNTS 65536
#define WS_NCHALF 66560
#define WS_SSE    67584
#define WS_EHI    67600
#define WS_ELO    100368

__device__ __forceinline__ float wave_reduce_add(float v) {
#pragma unroll
    for (int o = 32; o > 0; o >>= 1) v += __shfl_xor(v, o, 64);
    return v;
}

__device__ __forceinline__ unsigned short bf_rne(float f) {
    unsigned int u = __float_as_uint(f);
    unsigned int r = u + 0x7fffu + ((u >> 16) & 1u);
    return (unsigned short)(r >> 16);
}

// Zero dw/counts/sse; split E into bf16 hi/lo; nchalf. grid 256 x 256.
__global__ __launch_bounds__(256) void prep_kernel(const float* __restrict__ E,
                                                   float* __restrict__ ws) {
    const int bid = blockIdx.x, tid = threadIdx.x;
    const int id = bid * 256 + tid;            // element of E (k = id>>6, c = id&63)
    ws[id] = 0.0f;                             // dw
    if (bid < 4) ws[WS_COUNTS + bid * 256 + tid] = 0.0f;
    if (bid == 4 && tid == 0) ws[WS_SSE] = 0.0f;
    const float v = E[id];
    const unsigned short h = bf_rne(v);
    const float hf = __uint_as_float((unsigned int)h << 16);
    const unsigned short l = bf_rne(v - hf);
    ((unsigned short*)(ws + WS_EHI))[id] = h;
    ((unsigned short*)(ws + WS_ELO))[id] = l;
    const int lane = tid & 63;
    const float s = wave_reduce_add(v * v);
    if (lane == 0) ws[WS_NCHALF + (id >> 6)] = -0.5f * s;
}

// Main: MFMA scores + top-2 + fp64 re-rank + all scatter outputs.
// grid 512 x 256; each block = 128 tokens.
// __launch_bounds__(256, 2): only 2 waves/SIMD are reachable with this grid
// (512 blocks / 256 CUs x 4 waves), so give the register allocator the full
// 256-VGPR budget. The prior build pinned VGPR=84 and spilled the top-2
// select state to scratch -> ~200cy L2 round-trips inside the K-loop, which
// is what kept every pipe <20% busy (R0 counters).
__global__ __launch_bounds__(256, 2) void vq_main(const float* __restrict__ x,
                                                  const float* __restrict__ E,
                                                  float* __restrict__ out,
                                                  float* __restrict__ ws) {
    const int tid = threadIdx.x;
    const int lane = tid & 63;
    const int w = tid >> 6;
    const int blk = blockIdx.x;
    const int b = blk >> 5;            // batch
    const int hw0 = (blk & 31) << 7;   // hw offset (128 tokens)
    const int tok0 = blk << 7;

    __shared__ float xs[128 * 68];     // [token][dim], stride 68 keeps rows 16B-aligned
    __shared__ int i1sh[128], i2sh[128], idx_sh[128];

    float* enc = out + 1 + (size_t)4194304;
    f32x4* encb4 = (f32x4*)(enc + (size_t)tok0 * 1024);   // this block's 512 KB enc region

    // Stage x tile (fully coalesced: consecutive tid -> consecutive hw).
    {
        const float* xb = x + ((size_t)b << 18) + hw0;
#pragma unroll
        for (int cc = 0; cc < 32; ++cc) {
            const int id = cc * 256 + tid;
            const int c = id >> 7, t = id & 127;
            xs[t * 68 + c] = xb[((size_t)c << 12) + t];
        }
    }
    __syncthreads();

    const int q = lane >> 4, m = lane & 15;

    // A fragments: 2 row-tiles (16 tokens each) x 2 K-slices x (hi,lo).
    bf16x8 Ah[2][2], Al[2][2];
#pragma unroll
    for (int t = 0; t < 2; ++t) {
        const int tok = w * 32 + t * 16 + m;
#pragma unroll
        for (int s = 0; s < 2; ++s) {
            const float* p = &xs[tok * 68 + s * 32 + q * 8];
            ushort8 hu, lu;
#pragma unroll
            for (int j = 0; j < 8; ++j) {
                const float f = p[j];
                const unsigned short h = bf_rne(f);
                const float hf = __uint_as_float((unsigned int)h << 16);
                hu[j] = h;
                lu[j] = bf_rne(f - hf);
            }
            Ah[t][s] = __builtin_bit_cast(bf16x8, hu);
            Al[t][s] = __builtin_bit_cast(bf16x8, lu);
        }
    }

    const ushort8* __restrict__ Ehp = (const ushort8*)(ws + WS_EHI);  // [K][8] groups of 8 dims
    const ushort8* __restrict__ Elp = (const ushort8*)(ws + WS_ELO);
    const float* __restrict__ ncp = ws + WS_NCHALF;

    // Per-lane running top-2 per C/D row (4 regs x 2 tiles).
    float b1[2][4], b2[2][4];
    int i1[2][4], i2[2][4];
#pragma unroll
    for (int t = 0; t < 2; ++t)
#pragma unroll
        for (int r = 0; r < 4; ++r) { b1[t][r] = -1e30f; b2[t][r] = -1e30f; i1[t][r] = 0; i2[t][r] = 1; }

    // Depth-2 register prefetch of B fragments (static slot indices; rule #20).
    ushort8 p0h[2], p1h[2], p0l[2], p1l[2];
    float pnc[2];
#pragma unroll
    for (int s = 0; s < 2; ++s) {
        const int code = s * 16 + m;
        p0h[s] = Ehp[code * 8 + q];
        p1h[s] = Ehp[code * 8 + 4 + q];
        p0l[s] = Elp[code * 8 + q];
        p1l[s] = Elp[code * 8 + 4 + q];
        pnc[s] = ncp[code];
    }

    const f32x4 z4 = {0.0f, 0.0f, 0.0f, 0.0f};

#define VQ_STEP(S, CK)                                                          \
    {                                                                           \
        const bf16x8 bh0 = __builtin_bit_cast(bf16x8, p0h[S]);                  \
        const bf16x8 bh1 = __builtin_bit_cast(bf16x8, p1h[S]);                  \
        const bf16x8 bl0 = __builtin_bit_cast(bf16x8, p0l[S]);                  \
        const bf16x8 bl1 = __builtin_bit_cast(bf16x8, p1l[S]);                  \
        const float nc = pnc[S];                                                \
        if ((CK) + 2 < 64) {                                                    \
            const int code = ((CK) + 2) * 16 + m;                               \
            p0h[S] = Ehp[code * 8 + q];                                         \
            p1h[S] = Ehp[code * 8 + 4 + q];                                     \
            p0l[S] = Elp[code * 8 + q];                                         \
            p1l[S] = Elp[code * 8 + 4 + q];                                     \
            pnc[S] = ncp[code];                                                 \
        }                                                                       \
        /* interleaved one-hot zero-fill: 2 x 16B NT stores per thread per step \
           covers 64*512*16B = 512 KB = this block's 128 enc rows exactly. */   \
        {                                                                       \
            const int zslot = (CK) * 512 + tid;                                 \
            __builtin_nontemporal_store(z4, encb4 + zslot);                     \
            __builtin_nontemporal_store(z4, encb4 + zslot + 256);               \
        }                                                                       \
        const int idx = (CK) * 16 + m;                                          \
        _Pragma("unroll")                                                       \
        for (int t = 0; t < 2; ++t) {                                           \
            f32x4 acc = {nc, nc, nc, nc}; /* score = x.e - 0.5||e||^2 */        \
            acc = __builtin_amdgcn_mfma_f32_16x16x32_bf16(Ah[t][0], bh0, acc, 0, 0, 0); \
            acc = __builtin_amdgcn_mfma_f32_16x16x32_bf16(Ah[t][1], bh1, acc, 0, 0, 0); \
            acc = __builtin_amdgcn_mfma_f32_16x16x32_bf16(Al[t][0], bh0, acc, 0, 0, 0); \
            acc = __builtin_amdgcn_mfma_f32_16x16x32_bf16(Al[t][1], bh1, acc, 0, 0, 0); \
            acc = __builtin_amdgcn_mfma_f32_16x16x32_bf16(Ah[t][0], bl0, acc, 0, 0, 0); \
            acc = __builtin_amdgcn_mfma_f32_16x16x32_bf16(Ah[t][1], bl1, acc, 0, 0, 0); \
            _Pragma("unroll")                                                   \
            for (int r = 0; r < 4; ++r) {                                       \
                const float s = acc[r];                                         \
                const bool cA = s > b1[t][r];                                   \
                const bool cB = s > b2[t][r];                                   \
                b2[t][r] = cA ? b1[t][r] : (cB ? s : b2[t][r]);                 \
                i2[t][r] = cA ? i1[t][r] : (cB ? idx : i2[t][r]);               \
                b1[t][r] = cA ? s : b1[t][r];                                   \
                i1[t][r] = cA ? idx : i1[t][r];                                 \
            }                                                                   \
        }                                                                       \
    }

    for (int j = 0; j < 32; ++j) {
        VQ_STEP(0, 2 * j)
        VQ_STEP(1, 2 * j + 1)
    }
#undef VQ_STEP

    // Merge top-2 across the 16 lanes of each quad-group (cols of the row).
#pragma unroll
    for (int d = 1; d < 16; d <<= 1) {
#pragma unroll
        for (int t = 0; t < 2; ++t)
#pragma unroll
            for (int r = 0; r < 4; ++r) {
                const float ob1 = __shfl_xor(b1[t][r], d, 64);
                const int   oi1 = __shfl_xor(i1[t][r], d, 64);
                const float ob2 = __shfl_xor(b2[t][r], d, 64);
                const int   oi2 = __shfl_xor(i2[t][r], d, 64);
                const bool wv = ob1 > b1[t][r];
                const float t1 = wv ? ob1 : b1[t][r]; const int ti1 = wv ? oi1 : i1[t][r];
                const float sA = wv ? b1[t][r] : ob1; const int siA = wv ? i1[t][r] : oi1;
                const float sB = wv ? ob2 : b2[t][r]; const int siB = wv ? oi2 : i2[t][r];
                const bool w2 = sB > sA;
                b1[t][r] = t1; i1[t][r] = ti1;
                b2[t][r] = w2 ? sB : sA; i2[t][r] = w2 ? siB : siA;
            }
    }
    if (m == 0) {   // quad leaders publish rows 4q+r of each tile
#pragma unroll
        for (int t = 0; t < 2; ++t)
#pragma unroll
            for (int r = 0; r < 4; ++r) {
                const int tokL = w * 32 + t * 16 + q * 4 + r;
                i1sh[tokL] = i1[t][r];
                i2sh[tokL] = i2[t][r];
            }
    }

    // fp64 re-rank of the two candidates (same wave -> no barrier needed).
    float dval = 0.0f;
    if (lane < 32) {
        const int tokL = w * 32 + lane;
        const int I1 = i1sh[tokL], I2 = i2sh[tokL];
        const int ca = I1 < I2 ? I1 : I2;
        const int cb = I1 < I2 ? I2 : I1;
        const float* Ea = E + ca * 64;
        const float* Eb = E + cb * 64;
        const float* xr = &xs[tokL * 68];
        double sa = 0, ea = 0, sb = 0, eb = 0, x2 = 0;
#pragma unroll 8
        for (int c = 0; c < 64; ++c) {
            const double xv = (double)xr[c];
            const double va = (double)Ea[c], vb = (double)Eb[c];
            sa += xv * va; ea += va * va;
            sb += xv * vb; eb += vb * vb;
            x2 += xv * xv;
        }
        const double qa = ea - 2.0 * sa;
        const double qb = eb - 2.0 * sb;
        int best; double qq;
        if (qb < qa) { best = cb; qq = qb; } else { best = ca; qq = qa; }
        idx_sh[tokL] = best;
        float dd = (float)(qq + x2);
        dval = dd < 0.f ? 0.f : dd;
        atomicAdd(&ws[WS_COUNTS + best], 1.0f);
    }
    const float ssum = wave_reduce_add(dval);
    if (lane == 0) atomicAdd(&ws[WS_SSE], ssum);
    __syncthreads();   // also drains the NT zero stores before the 1.0 writes

    // q_st output (reference order: x + (e - x)).
    float* outq = out + 1;
#pragma unroll
    for (int cc = 0; cc < 32; ++cc) {
        const int id = cc * 256 + tid;
        const int c = id >> 7, t = id & 127;
        const int kb = idx_sh[t];
        const float xv = xs[t * 68 + c];
        const float eq = E[kb * 64 + c];
        outq[((size_t)(b * 64 + c) << 12) + hw0 + t] = xv + (eq - xv);
    }
    // dw scatter-add: lane = dim (coalesced atomics), wave-uniform row.
#pragma unroll 4
    for (int tt = 0; tt < 32; ++tt) {
        const int t = w * 32 + tt;
        const int kb = idx_sh[t];
        atomicAdd(&ws[kb * 64 + lane], xs[t * 68 + lane]);
    }
    // one-hot encodings: rows pre-zeroed in the K-loop; write only the 1.0 entries.
    {
        if (tid < 128) {
            const int kb = idx_sh[tid];
            __builtin_nontemporal_store(1.0f, enc + (size_t)(tok0 + tid) * 1024 + kb);
        }
    }
}

// new_cs (Laplace-smoothed) + loss. 1 block x 1024.
__global__ __launch_bounds__(1024) void fin_cs(const float* __restrict__ cs_in,
                                               float* __restrict__ out,
                                               const float* __restrict__ ws) {
    __shared__ float red[16];
    __shared__ float n_sh;
    const int tid = threadIdx.x;
    const float raw = cs_in[tid] * DECAYF + ONEMF * ws[WS_COUNTS + tid];
    const float s = wave_reduce_add(raw);
    if ((tid & 63) == 0) red[tid >> 6] = s;
    __syncthreads();
    if (tid == 0) {
        float n = 0.f;
#pragma unroll
        for (int i = 0; i < 16; ++i) n += red[i];
        n_sh = n;
        out[0] = 0.25f * ws[WS_SSE] * (1.0f / 4194304.0f);  // loss
    }
    __syncthreads();
    const float n = n_sh;
    out[71368705 + tid] = (raw + EPSF) / (n + 1024.0f * EPSF) * n;
}

// new_ema_weight and new_embedding. grid 256 x 256.
__global__ __launch_bounds__(256) void fin_w(const float* __restrict__ emaw,
                                             float* __restrict__ out,
                                             const float* __restrict__ ws) {
    const int i = blockIdx.x * 256 + threadIdx.x;
    const float val = emaw[i] * DECAYF + ONEMF * ws[i];
    out[71369729 + i] = val;                               // new_ema_weight
    const float cs = out[71368705 + (i >> 6)];             // new_cs (from fin_cs)
    out[71303169 + i] = val / cs;                          // new_embedding
}

extern "C" void kernel_launch(void* const* d_in, const int* in_sizes, int n_in,
                              void* d_out, int out_size, void* d_ws, size_t ws_size,
                              hipStream_t stream) {
    const float* x    = (const float*)d_in[0];   // [16,64,64,64]
    const float* E    = (const float*)d_in[1];   // [1024,64]
    const float* cs   = (const float*)d_in[2];   // [1024]
    const float* emaw = (const float*)d_in[3];   // [1024,64]
    float* out = (float*)d_out;
    float* ws  = (float*)d_ws;

    prep_kernel<<<256, 256, 0, stream>>>(E, ws);
    vq_main<<<512, 256, 0, stream>>>(x, E, out, ws);
    fin_cs<<<1, 1024, 0, stream>>>(cs, out, ws);
    fin_w<<<256, 256, 0, stream>>>(emaw, out, ws);
}

// Round 8
// 363.515 us; speedup vs baseline: 1.2983x; 1.0491x over previous
//
#include <hip/hip_runtime.h>

#define DECAYF 0.99f
#define ONEMF 0.01f
#define EPSF 1e-5f

typedef __bf16 bf16x8 __attribute__((ext_vector_type(8)));
typedef float f32x4 __attribute__((ext_vector_type(4)));
typedef unsigned short ushort8 __attribute__((ext_vector_type(8)));

// ws layout (float indices):
// [0,65536)        dw accumulator (K*D)
// [65536,66560)    counts (K)
// [66560,67584)    nchalf = -0.5*||e_k||^2
// [67584]          sse
// [67600,100368)   E_hi as bf16 (ushort), row-major [K][D]
// [100368,133136)  E_lo as bf16 (ushort)
#define WS_COUNTS 65536
#define WS_NCHALF 66560
#define WS_SSE    67584
#define WS_EHI    67600
#define WS_ELO    100368

__device__ __forceinline__ float wave_reduce_add(float v) {
#pragma unroll
    for (int o = 32; o > 0; o >>= 1) v += __shfl_xor(v, o, 64);
    return v;
}

__device__ __forceinline__ unsigned short bf_rne(float f) {
    unsigned int u = __float_as_uint(f);
    unsigned int r = u + 0x7fffu + ((u >> 16) & 1u);
    return (unsigned short)(r >> 16);
}

// Zero dw/counts/sse; split E into bf16 hi/lo; nchalf. grid 256 x 256.
__global__ __launch_bounds__(256) void prep_kernel(const float* __restrict__ E,
                                                   float* __restrict__ ws) {
    const int bid = blockIdx.x, tid = threadIdx.x;
    const int id = bid * 256 + tid;            // element of E (k = id>>6, c = id&63)
    ws[id] = 0.0f;                             // dw
    if (bid < 4) ws[WS_COUNTS + bid * 256 + tid] = 0.0f;
    if (bid == 4 && tid == 0) ws[WS_SSE] = 0.0f;
    const float v = E[id];
    const unsigned short h = bf_rne(v);
    const float hf = __uint_as_float((unsigned int)h << 16);
    const unsigned short l = bf_rne(v - hf);
    ((unsigned short*)(ws + WS_EHI))[id] = h;
    ((unsigned short*)(ws + WS_ELO))[id] = l;
    const int lane = tid & 63;
    const float s = wave_reduce_add(v * v);
    if (lane == 0) ws[WS_NCHALF + (id >> 6)] = -0.5f * s;
}

// Main: MFMA scores + top-2 + fp64 re-rank + all scatter outputs.
// grid 512 x 256; each block = 128 tokens.
// B (codebook) is staged through LDS, double-buffered in 32-code chunks, with
// XOR-swizzled rows (group ^= row&7) so ds_write_b128/ds_read_b128 are
// bank-balanced. This replaces per-step global B-gathers (512 MB of repeated
// L2/L3 traffic, latency-exposed every iteration -- the surviving suspect for
// the ~150us loop) with one-pass staging (128 MB) + LDS-class read latency.
__global__ __launch_bounds__(256, 2) void vq_main(const float* __restrict__ x,
                                                  const float* __restrict__ E,
                                                  float* __restrict__ out,
                                                  float* __restrict__ ws) {
    const int tid = threadIdx.x;
    const int lane = tid & 63;
    const int w = tid >> 6;
    const int q = lane >> 4, m = lane & 15;
    const int blk = blockIdx.x;
    const int b = blk >> 5;            // batch
    const int hw0 = (blk & 31) << 7;   // hw offset (128 tokens)
    const int tok0 = blk << 7;

    __shared__ float xs[128 * 68];     // [token][dim], stride 68 keeps rows 16B-aligned
    __shared__ int i1sh[128], i2sh[128], idx_sh[128];
    // Double-buffered B chunk: [hi 4096B][lo 4096B][nchalf 128B] per buffer.
    __shared__ char lds_b[2][8320];

    float* enc = out + 1 + (size_t)4194304;
    f32x4* encb4 = (f32x4*)(enc + (size_t)tok0 * 1024);   // this block's 512 KB enc region

    const unsigned short* __restrict__ EHIu = (const unsigned short*)(ws + WS_EHI);
    const unsigned short* __restrict__ ELOu = (const unsigned short*)(ws + WS_ELO);
    const float* __restrict__ ncp = ws + WS_NCHALF;

    // Stage x tile (fully coalesced: consecutive tid -> consecutive hw).
    {
        const float* xb = x + ((size_t)b << 18) + hw0;
#pragma unroll
        for (int cc = 0; cc < 32; ++cc) {
            const int id = cc * 256 + tid;
            const int c = id >> 7, t = id & 127;
            xs[t * 68 + c] = xb[((size_t)c << 12) + t];
        }
    }

    // Swizzled LDS destination for this thread's 16B staging unit:
    // unit u = tid: row cl = u>>3 (0..31), logical group g = u&7,
    // physical group pg = g ^ (cl&7)  -> balanced banks for write AND read.
    const int cl_s = tid >> 3, g_s = tid & 7;
    const int dst_s = cl_s * 128 + ((g_s ^ (cl_s & 7)) << 4);

    // Prologue: stage chunk 0 directly.
    *(f32x4*)(lds_b[0] + dst_s)        = *(const f32x4*)(EHIu + tid * 8);
    *(f32x4*)(lds_b[0] + 4096 + dst_s) = *(const f32x4*)(ELOu + tid * 8);
    if (tid < 32) *(float*)(lds_b[0] + 8192 + tid * 4) = ncp[tid];
    __syncthreads();

    // A fragments: 2 row-tiles (16 tokens each) x 2 K-slices x (hi,lo).
    bf16x8 Ah[2][2], Al[2][2];
#pragma unroll
    for (int t = 0; t < 2; ++t) {
        const int tok = w * 32 + t * 16 + m;
#pragma unroll
        for (int s = 0; s < 2; ++s) {
            const float* p = &xs[tok * 68 + s * 32 + q * 8];
            ushort8 hu, lu;
#pragma unroll
            for (int j = 0; j < 8; ++j) {
                const float f = p[j];
                const unsigned short h = bf_rne(f);
                const float hf = __uint_as_float((unsigned int)h << 16);
                hu[j] = h;
                lu[j] = bf_rne(f - hf);
            }
            Ah[t][s] = __builtin_bit_cast(bf16x8, hu);
            Al[t][s] = __builtin_bit_cast(bf16x8, lu);
        }
    }

    // Per-lane running top-2 per C/D row (4 regs x 2 tiles).
    float b1[2][4], b2[2][4];
    int i1[2][4], i2[2][4];
#pragma unroll
    for (int t = 0; t < 2; ++t)
#pragma unroll
        for (int r = 0; r < 4; ++r) { b1[t][r] = -1e30f; b2[t][r] = -1e30f; i1[t][r] = 0; i2[t][r] = 1; }

    const f32x4 z4 = {0.0f, 0.0f, 0.0f, 0.0f};
    const int hm = m & 7;
    const int off0 = (q ^ hm) << 4;           // group q  (dims q*8..q*8+8)
    const int off1 = ((4 + q) ^ hm) << 4;     // group 4+q (dims 32+q*8..)

    // 32 chunks x 2 steps. T14 split: issue next-chunk loads at chunk open,
    // ds_write after compute, one barrier per chunk.
    for (int kc = 0; kc < 32; ++kc) {
        f32x4 sH = z4, sL = z4; float sN = 0.0f;
        if (kc < 31) {
            sH = *(const f32x4*)(EHIu + (kc + 1) * 2048 + tid * 8);
            sL = *(const f32x4*)(ELOu + (kc + 1) * 2048 + tid * 8);
            if (tid < 32) sN = ncp[(kc + 1) * 32 + tid];
        }
        const char* bufc = lds_b[kc & 1];

#define VQ_STEP(S)                                                              \
    {                                                                           \
        const int cl = (S) * 16 + m;                                            \
        const char* rowp = bufc + cl * 128;                                     \
        const bf16x8 bh0 = *(const bf16x8*)(rowp + off0);                       \
        const bf16x8 bh1 = *(const bf16x8*)(rowp + off1);                       \
        const bf16x8 bl0 = *(const bf16x8*)(rowp + 4096 + off0);                \
        const bf16x8 bl1 = *(const bf16x8*)(rowp + 4096 + off1);                \
        const float nc = *(const float*)(bufc + 8192 + cl * 4);                 \
        {   /* interleaved one-hot zero-fill: 2 x 16B NT stores per step */     \
            const int zslot = (kc * 2 + (S)) * 512 + tid;                       \
            __builtin_nontemporal_store(z4, encb4 + zslot);                     \
            __builtin_nontemporal_store(z4, encb4 + zslot + 256);               \
        }                                                                       \
        const int idx = kc * 32 + cl;                                           \
        _Pragma("unroll")                                                       \
        for (int t = 0; t < 2; ++t) {                                           \
            f32x4 acc = {nc, nc, nc, nc}; /* score = x.e - 0.5||e||^2 */        \
            acc = __builtin_amdgcn_mfma_f32_16x16x32_bf16(Ah[t][0], bh0, acc, 0, 0, 0); \
            acc = __builtin_amdgcn_mfma_f32_16x16x32_bf16(Ah[t][1], bh1, acc, 0, 0, 0); \
            acc = __builtin_amdgcn_mfma_f32_16x16x32_bf16(Al[t][0], bh0, acc, 0, 0, 0); \
            acc = __builtin_amdgcn_mfma_f32_16x16x32_bf16(Al[t][1], bh1, acc, 0, 0, 0); \
            acc = __builtin_amdgcn_mfma_f32_16x16x32_bf16(Ah[t][0], bl0, acc, 0, 0, 0); \
            acc = __builtin_amdgcn_mfma_f32_16x16x32_bf16(Ah[t][1], bl1, acc, 0, 0, 0); \
            _Pragma("unroll")                                                   \
            for (int r = 0; r < 4; ++r) {                                       \
                const float s = acc[r];                                         \
                const bool cA = s > b1[t][r];                                   \
                const bool cB = s > b2[t][r];                                   \
                b2[t][r] = cA ? b1[t][r] : (cB ? s : b2[t][r]);                 \
                i2[t][r] = cA ? i1[t][r] : (cB ? idx : i2[t][r]);               \
                b1[t][r] = cA ? s : b1[t][r];                                   \
                i1[t][r] = cA ? idx : i1[t][r];                                 \
            }                                                                   \
        }                                                                       \
    }

        VQ_STEP(0)
        VQ_STEP(1)
#undef VQ_STEP

        if (kc < 31) {
            char* bufn = lds_b[(kc + 1) & 1];
            *(f32x4*)(bufn + dst_s)        = sH;
            *(f32x4*)(bufn + 4096 + dst_s) = sL;
            if (tid < 32) *(float*)(bufn + 8192 + tid * 4) = sN;
        }
        __syncthreads();
    }

    // Merge top-2 across the 16 lanes of each quad-group (cols of the row).
#pragma unroll
    for (int d = 1; d < 16; d <<= 1) {
#pragma unroll
        for (int t = 0; t < 2; ++t)
#pragma unroll
            for (int r = 0; r < 4; ++r) {
                const float ob1 = __shfl_xor(b1[t][r], d, 64);
                const int   oi1 = __shfl_xor(i1[t][r], d, 64);
                const float ob2 = __shfl_xor(b2[t][r], d, 64);
                const int   oi2 = __shfl_xor(i2[t][r], d, 64);
                const bool wv = ob1 > b1[t][r];
                const float t1 = wv ? ob1 : b1[t][r]; const int ti1 = wv ? oi1 : i1[t][r];
                const float sA = wv ? b1[t][r] : ob1; const int siA = wv ? i1[t][r] : oi1;
                const float sB = wv ? ob2 : b2[t][r]; const int siB = wv ? oi2 : i2[t][r];
                const bool w2 = sB > sA;
                b1[t][r] = t1; i1[t][r] = ti1;
                b2[t][r] = w2 ? sB : sA; i2[t][r] = w2 ? siB : siA;
            }
    }
    if (m == 0) {   // quad leaders publish rows 4q+r of each tile
#pragma unroll
        for (int t = 0; t < 2; ++t)
#pragma unroll
            for (int r = 0; r < 4; ++r) {
                const int tokL = w * 32 + t * 16 + q * 4 + r;
                i1sh[tokL] = i1[t][r];
                i2sh[tokL] = i2[t][r];
            }
    }

    // fp64 re-rank of the two candidates (same wave -> no barrier needed).
    float dval = 0.0f;
    if (lane < 32) {
        const int tokL = w * 32 + lane;
        const int I1 = i1sh[tokL], I2 = i2sh[tokL];
        const int ca = I1 < I2 ? I1 : I2;
        const int cb = I1 < I2 ? I2 : I1;
        const float* Ea = E + ca * 64;
        const float* Eb = E + cb * 64;
        const float* xr = &xs[tokL * 68];
        double sa = 0, ea = 0, sb = 0, eb = 0, x2 = 0;
#pragma unroll 8
        for (int c = 0; c < 64; ++c) {
            const double xv = (double)xr[c];
            const double va = (double)Ea[c], vb = (double)Eb[c];
            sa += xv * va; ea += va * va;
            sb += xv * vb; eb += vb * vb;
            x2 += xv * xv;
        }
        const double qa = ea - 2.0 * sa;
        const double qb = eb - 2.0 * sb;
        int best; double qq;
        if (qb < qa) { best = cb; qq = qb; } else { best = ca; qq = qa; }
        idx_sh[tokL] = best;
        float dd = (float)(qq + x2);
        dval = dd < 0.f ? 0.f : dd;
        atomicAdd(&ws[WS_COUNTS + best], 1.0f);
    }
    const float ssum = wave_reduce_add(dval);
    if (lane == 0) atomicAdd(&ws[WS_SSE], ssum);
    __syncthreads();   // also drains the NT zero stores before the 1.0 writes

    // q_st output (reference order: x + (e - x)).
    float* outq = out + 1;
#pragma unroll
    for (int cc = 0; cc < 32; ++cc) {
        const int id = cc * 256 + tid;
        const int c = id >> 7, t = id & 127;
        const int kb = idx_sh[t];
        const float xv = xs[t * 68 + c];
        const float eq = E[kb * 64 + c];
        outq[((size_t)(b * 64 + c) << 12) + hw0 + t] = xv + (eq - xv);
    }
    // dw scatter-add: lane = dim (coalesced atomics), wave-uniform row.
#pragma unroll 4
    for (int tt = 0; tt < 32; ++tt) {
        const int t = w * 32 + tt;
        const int kb = idx_sh[t];
        atomicAdd(&ws[kb * 64 + lane], xs[t * 68 + lane]);
    }
    // one-hot encodings: rows pre-zeroed in the K-loop; write only the 1.0 entries.
    {
        if (tid < 128) {
            const int kb = idx_sh[tid];
            __builtin_nontemporal_store(1.0f, enc + (size_t)(tok0 + tid) * 1024 + kb);
        }
    }
}

// new_cs (Laplace-smoothed) + loss. 1 block x 1024.
__global__ __launch_bounds__(1024) void fin_cs(const float* __restrict__ cs_in,
                                               float* __restrict__ out,
                                               const float* __restrict__ ws) {
    __shared__ float red[16];
    __shared__ float n_sh;
    const int tid = threadIdx.x;
    const float raw = cs_in[tid] * DECAYF + ONEMF * ws[WS_COUNTS + tid];
    const float s = wave_reduce_add(raw);
    if ((tid & 63) == 0) red[tid >> 6] = s;
    __syncthreads();
    if (tid == 0) {
        float n = 0.f;
#pragma unroll
        for (int i = 0; i < 16; ++i) n += red[i];
        n_sh = n;
        out[0] = 0.25f * ws[WS_SSE] * (1.0f / 4194304.0f);  // loss
    }
    __syncthreads();
    const float n = n_sh;
    out[71368705 + tid] = (raw + EPSF) / (n + 1024.0f * EPSF) * n;
}

// new_ema_weight and new_embedding. grid 256 x 256.
__global__ __launch_bounds__(256) void fin_w(const float* __restrict__ emaw,
                                             float* __restrict__ out,
                                             const float* __restrict__ ws) {
    const int i = blockIdx.x * 256 + threadIdx.x;
    const float val = emaw[i] * DECAYF + ONEMF * ws[i];
    out[71369729 + i] = val;                               // new_ema_weight
    const float cs = out[71368705 + (i >> 6)];             // new_cs (from fin_cs)
    out[71303169 + i] = val / cs;                          // new_embedding
}

extern "C" void kernel_launch(void* const* d_in, const int* in_sizes, int n_in,
                              void* d_out, int out_size, void* d_ws, size_t ws_size,
                              hipStream_t stream) {
    const float* x    = (const float*)d_in[0];   // [16,64,64,64]
    const float* E    = (const float*)d_in[1];   // [1024,64]
    const float* cs   = (const float*)d_in[2];   // [1024]
    const float* emaw = (const float*)d_in[3];   // [1024,64]
    float* out = (float*)d_out;
    float* ws  = (float*)d_ws;

    prep_kernel<<<256, 256, 0, stream>>>(E, ws);
    vq_main<<<512, 256, 0, stream>>>(x, E, out, ws);
    fin_cs<<<1, 1024, 0, stream>>>(cs, out, ws);
    fin_w<<<256, 256, 0, stream>>>(emaw, out, ws);
}

// Round 9
// 345.419 us; speedup vs baseline: 1.3663x; 1.0524x over previous
//
#include <hip/hip_runtime.h>

#define DECAYF 0.99f
#define ONEMF 0.01f
#define EPSF 1e-5f

typedef __bf16 bf16x8 __attribute__((ext_vector_type(8)));
typedef float f32x4 __attribute__((ext_vector_type(4)));
typedef unsigned short ushort8 __attribute__((ext_vector_type(8)));

// ws layout (float indices):
// [0,65536)        dw accumulator (K*D)
// [65536,66560)    counts (K)
// [66560,67584)    nchalf = -0.5*||e_k||^2
// [67584]          sse
// [67600,100368)   E_hi as bf16 (ushort), row-major [K][D]
// [100368,133136)  E_lo as bf16 (ushort)
#define WS_COUNTS 65536
#define WS_NCHALF 66560
#define WS_SSE    67584
#define WS_EHI    67600
#define WS_ELO    100368

__device__ __forceinline__ float wave_reduce_add(float v) {
#pragma unroll
    for (int o = 32; o > 0; o >>= 1) v += __shfl_xor(v, o, 64);
    return v;
}

__device__ __forceinline__ unsigned short bf_rne(float f) {
    unsigned int u = __float_as_uint(f);
    unsigned int r = u + 0x7fffu + ((u >> 16) & 1u);
    return (unsigned short)(r >> 16);
}

// Zero dw/counts/sse; split E into bf16 hi/lo; nchalf. grid 256 x 256.
__global__ __launch_bounds__(256) void prep_kernel(const float* __restrict__ E,
                                                   float* __restrict__ ws) {
    const int bid = blockIdx.x, tid = threadIdx.x;
    const int id = bid * 256 + tid;            // element of E (k = id>>6, c = id&63)
    ws[id] = 0.0f;                             // dw
    if (bid < 4) ws[WS_COUNTS + bid * 256 + tid] = 0.0f;
    if (bid == 4 && tid == 0) ws[WS_SSE] = 0.0f;
    const float v = E[id];
    const unsigned short h = bf_rne(v);
    const float hf = __uint_as_float((unsigned int)h << 16);
    const unsigned short l = bf_rne(v - hf);
    ((unsigned short*)(ws + WS_EHI))[id] = h;
    ((unsigned short*)(ws + WS_ELO))[id] = l;
    const int lane = tid & 63;
    const float s = wave_reduce_add(v * v);
    if (lane == 0) ws[WS_NCHALF + (id >> 6)] = -0.5f * s;
}

// Main: MFMA scores + top-2 + fp64 re-rank + all scatter outputs.
// grid 512 x 256; each block = 128 tokens.
// B staged via LDS in 64-code double-buffered chunks (XOR-swizzled rows).
// KEY CHANGE (T4): in-loop barriers are raw s_barrier + lgkmcnt(0) only --
// hipcc's __syncthreads() lowering adds `s_waitcnt vmcnt(0)` which drained
// every outstanding NT enc-store + staging load at HBM latency once per chunk
// (both co-resident blocks in lockstep -> pure stall). NT stores now stay in
// flight across chunk boundaries; the compiler's counted vmcnt before the
// ds_write (register dep) leaves younger stores outstanding.
__global__ __launch_bounds__(256, 2) void vq_main(const float* __restrict__ x,
                                                  const float* __restrict__ E,
                                                  float* __restrict__ out,
                                                  float* __restrict__ ws) {
    const int tid = threadIdx.x;
    const int lane = tid & 63;
    const int w = tid >> 6;
    const int q = lane >> 4, m = lane & 15;
    const int blk = blockIdx.x;
    const int b = blk >> 5;            // batch
    const int hw0 = (blk & 31) << 7;   // hw offset (128 tokens)
    const int tok0 = blk << 7;

    __shared__ float xs[128 * 68];     // [token][dim], stride 68 keeps rows 16B-aligned
    __shared__ int i1sh[128], i2sh[128], idx_sh[128];
    // Double-buffered 64-code chunk: [hi 8192B][lo 8192B][nchalf 256B].
    __shared__ char lds_b[2][16640];

    float* enc = out + 1 + (size_t)4194304;
    f32x4* encb4 = (f32x4*)(enc + (size_t)tok0 * 1024);   // this block's 512 KB enc region

    const unsigned short* __restrict__ EHIu = (const unsigned short*)(ws + WS_EHI);
    const unsigned short* __restrict__ ELOu = (const unsigned short*)(ws + WS_ELO);
    const float* __restrict__ ncp = ws + WS_NCHALF;

    // Stage x tile (fully coalesced: consecutive tid -> consecutive hw).
    {
        const float* xb = x + ((size_t)b << 18) + hw0;
#pragma unroll
        for (int cc = 0; cc < 32; ++cc) {
            const int id = cc * 256 + tid;
            const int c = id >> 7, t = id & 127;
            xs[t * 68 + c] = xb[((size_t)c << 12) + t];
        }
    }

    // Swizzled LDS destinations for this thread's two 16B staging units:
    // unit u: row cl = u>>3 (0..63), group g = u&7, phys pg = g ^ (cl&7).
    // For u and u+256, (cl&7) is equal -> dst1 = dst0 + 4096.
    const int cl_s = tid >> 3, g_s = tid & 7;
    const int dst0 = cl_s * 128 + ((g_s ^ (cl_s & 7)) << 4);

    // Prologue: stage chunk 0 (codes 0..63) directly.
    *(f32x4*)(lds_b[0] + dst0)               = *(const f32x4*)(EHIu + tid * 8);
    *(f32x4*)(lds_b[0] + dst0 + 4096)        = *(const f32x4*)(EHIu + (tid + 256) * 8);
    *(f32x4*)(lds_b[0] + 8192 + dst0)        = *(const f32x4*)(ELOu + tid * 8);
    *(f32x4*)(lds_b[0] + 8192 + dst0 + 4096) = *(const f32x4*)(ELOu + (tid + 256) * 8);
    if (tid < 64) *(float*)(lds_b[0] + 16384 + tid * 4) = ncp[tid];
    __syncthreads();

    // A fragments: 2 row-tiles (16 tokens each) x 2 K-slices x (hi,lo).
    bf16x8 Ah[2][2], Al[2][2];
#pragma unroll
    for (int t = 0; t < 2; ++t) {
        const int tok = w * 32 + t * 16 + m;
#pragma unroll
        for (int s = 0; s < 2; ++s) {
            const float* p = &xs[tok * 68 + s * 32 + q * 8];
            ushort8 hu, lu;
#pragma unroll
            for (int j = 0; j < 8; ++j) {
                const float f = p[j];
                const unsigned short h = bf_rne(f);
                const float hf = __uint_as_float((unsigned int)h << 16);
                hu[j] = h;
                lu[j] = bf_rne(f - hf);
            }
            Ah[t][s] = __builtin_bit_cast(bf16x8, hu);
            Al[t][s] = __builtin_bit_cast(bf16x8, lu);
        }
    }

    // Per-lane running top-2 per C/D row (4 regs x 2 tiles).
    float b1[2][4], b2[2][4];
    int i1[2][4], i2[2][4];
#pragma unroll
    for (int t = 0; t < 2; ++t)
#pragma unroll
        for (int r = 0; r < 4; ++r) { b1[t][r] = -1e30f; b2[t][r] = -1e30f; i1[t][r] = 0; i2[t][r] = 1; }

    const f32x4 z4 = {0.0f, 0.0f, 0.0f, 0.0f};
    const int hm = m & 7;
    const int off0 = (q ^ hm) << 4;           // group q   (dims q*8..)
    const int off1 = ((4 + q) ^ hm) << 4;     // group 4+q (dims 32+q*8..)

    // 16 chunks x 4 steps. Issue-early: next-chunk loads + this chunk's batched
    // NT zero stores at chunk open; ds_write late; barrier WITHOUT vmcnt drain.
    for (int kc = 0; kc < 16; ++kc) {
        f32x4 sH0 = z4, sH1 = z4, sL0 = z4, sL1 = z4; float sN = 0.0f;
        if (kc < 15) {
            const int eb = (kc + 1) * 4096;
            sH0 = *(const f32x4*)(EHIu + eb + tid * 8);
            sH1 = *(const f32x4*)(EHIu + eb + (tid + 256) * 8);
            sL0 = *(const f32x4*)(ELOu + eb + tid * 8);
            sL1 = *(const f32x4*)(ELOu + eb + (tid + 256) * 8);
            if (tid < 64) sN = ncp[(kc + 1) * 64 + tid];
        }
        {   // batched one-hot zero-fill: 4 x 16B NT stores per thread per chunk;
            // 16 chunks x 2048 x 16B = this block's 128 enc rows exactly.
            const int zslot = kc * 2048 + tid;
            __builtin_nontemporal_store(z4, encb4 + zslot);
            __builtin_nontemporal_store(z4, encb4 + zslot + 512);
            __builtin_nontemporal_store(z4, encb4 + zslot + 1024);
            __builtin_nontemporal_store(z4, encb4 + zslot + 1536);
        }
        const char* bufc = lds_b[kc & 1];

#define VQ_STEP(S)                                                              \
    {                                                                           \
        const int cl = (S) * 16 + m;                                            \
        const char* rowp = bufc + cl * 128;                                     \
        const bf16x8 bh0 = *(const bf16x8*)(rowp + off0);                       \
        const bf16x8 bh1 = *(const bf16x8*)(rowp + off1);                       \
        const bf16x8 bl0 = *(const bf16x8*)(rowp + 8192 + off0);                \
        const bf16x8 bl1 = *(const bf16x8*)(rowp + 8192 + off1);                \
        const float nc = *(const float*)(bufc + 16384 + cl * 4);                \
        const int idx = kc * 64 + cl;                                           \
        _Pragma("unroll")                                                       \
        for (int t = 0; t < 2; ++t) {                                           \
            f32x4 acc = {nc, nc, nc, nc}; /* score = x.e - 0.5||e||^2 */        \
            acc = __builtin_amdgcn_mfma_f32_16x16x32_bf16(Ah[t][0], bh0, acc, 0, 0, 0); \
            acc = __builtin_amdgcn_mfma_f32_16x16x32_bf16(Ah[t][1], bh1, acc, 0, 0, 0); \
            acc = __builtin_amdgcn_mfma_f32_16x16x32_bf16(Al[t][0], bh0, acc, 0, 0, 0); \
            acc = __builtin_amdgcn_mfma_f32_16x16x32_bf16(Al[t][1], bh1, acc, 0, 0, 0); \
            acc = __builtin_amdgcn_mfma_f32_16x16x32_bf16(Ah[t][0], bl0, acc, 0, 0, 0); \
            acc = __builtin_amdgcn_mfma_f32_16x16x32_bf16(Ah[t][1], bl1, acc, 0, 0, 0); \
            _Pragma("unroll")                                                   \
            for (int r = 0; r < 4; ++r) {                                       \
                const float s = acc[r];                                         \
                const bool cA = s > b1[t][r];                                   \
                const bool cB = s > b2[t][r];                                   \
                b2[t][r] = cA ? b1[t][r] : (cB ? s : b2[t][r]);                 \
                i2[t][r] = cA ? i1[t][r] : (cB ? idx : i2[t][r]);               \
                b1[t][r] = cA ? s : b1[t][r];                                   \
                i1[t][r] = cA ? idx : i1[t][r];                                 \
            }                                                                   \
        }                                                                       \
    }

        VQ_STEP(0)
        VQ_STEP(1)
        VQ_STEP(2)
        VQ_STEP(3)
#undef VQ_STEP

        if (kc < 15) {
            char* bufn = lds_b[(kc + 1) & 1];
            *(f32x4*)(bufn + dst0)               = sH0;   // compiler emits counted
            *(f32x4*)(bufn + dst0 + 4096)        = sH1;   // vmcnt here (reg dep),
            *(f32x4*)(bufn + 8192 + dst0)        = sL0;   // NT stores stay in flight
            *(f32x4*)(bufn + 8192 + dst0 + 4096) = sL1;
            if (tid < 64) *(float*)(bufn + 16384 + tid * 4) = sN;
        }
        // Barrier WITHOUT vmcnt(0): order LDS ops only.
        asm volatile("s_waitcnt lgkmcnt(0)" ::: "memory");
        __builtin_amdgcn_s_barrier();
        __builtin_amdgcn_sched_barrier(0);
    }

    // Merge top-2 across the 16 lanes of each quad-group (cols of the row).
#pragma unroll
    for (int d = 1; d < 16; d <<= 1) {
#pragma unroll
        for (int t = 0; t < 2; ++t)
#pragma unroll
            for (int r = 0; r < 4; ++r) {
                const float ob1 = __shfl_xor(b1[t][r], d, 64);
                const int   oi1 = __shfl_xor(i1[t][r], d, 64);
                const float ob2 = __shfl_xor(b2[t][r], d, 64);
                const int   oi2 = __shfl_xor(i2[t][r], d, 64);
                const bool wv = ob1 > b1[t][r];
                const float t1 = wv ? ob1 : b1[t][r]; const int ti1 = wv ? oi1 : i1[t][r];
                const float sA = wv ? b1[t][r] : ob1; const int siA = wv ? i1[t][r] : oi1;
                const float sB = wv ? ob2 : b2[t][r]; const int siB = wv ? oi2 : i2[t][r];
                const bool w2 = sB > sA;
                b1[t][r] = t1; i1[t][r] = ti1;
                b2[t][r] = w2 ? sB : sA; i2[t][r] = w2 ? siB : siA;
            }
    }
    if (m == 0) {   // quad leaders publish rows 4q+r of each tile
#pragma unroll
        for (int t = 0; t < 2; ++t)
#pragma unroll
            for (int r = 0; r < 4; ++r) {
                const int tokL = w * 32 + t * 16 + q * 4 + r;
                i1sh[tokL] = i1[t][r];
                i2sh[tokL] = i2[t][r];
            }
    }

    // fp64 re-rank of the two candidates (same wave -> no barrier needed).
    float dval = 0.0f;
    if (lane < 32) {
        const int tokL = w * 32 + lane;
        const int I1 = i1sh[tokL], I2 = i2sh[tokL];
        const int ca = I1 < I2 ? I1 : I2;
        const int cb = I1 < I2 ? I2 : I1;
        const float* Ea = E + ca * 64;
        const float* Eb = E + cb * 64;
        const float* xr = &xs[tokL * 68];
        double sa = 0, ea = 0, sb = 0, eb = 0, x2 = 0;
#pragma unroll 8
        for (int c = 0; c < 64; ++c) {
            const double xv = (double)xr[c];
            const double va = (double)Ea[c], vb = (double)Eb[c];
            sa += xv * va; ea += va * va;
            sb += xv * vb; eb += vb * vb;
            x2 += xv * xv;
        }
        const double qa = ea - 2.0 * sa;
        const double qb = eb - 2.0 * sb;
        int best; double qq;
        if (qb < qa) { best = cb; qq = qb; } else { best = ca; qq = qa; }
        idx_sh[tokL] = best;
        float dd = (float)(qq + x2);
        dval = dd < 0.f ? 0.f : dd;
        atomicAdd(&ws[WS_COUNTS + best], 1.0f);
    }
    const float ssum = wave_reduce_add(dval);
    if (lane == 0) atomicAdd(&ws[WS_SSE], ssum);
    __syncthreads();   // FULL drain (vmcnt(0)): zero stores retire before 1.0 writes

    // q_st output (reference order: x + (e - x)).
    float* outq = out + 1;
#pragma unroll
    for (int cc = 0; cc < 32; ++cc) {
        const int id = cc * 256 + tid;
        const int c = id >> 7, t = id & 127;
        const int kb = idx_sh[t];
        const float xv = xs[t * 68 + c];
        const float eq = E[kb * 64 + c];
        outq[((size_t)(b * 64 + c) << 12) + hw0 + t] = xv + (eq - xv);
    }
    // dw scatter-add: lane = dim (coalesced atomics), wave-uniform row.
#pragma unroll 4
    for (int tt = 0; tt < 32; ++tt) {
        const int t = w * 32 + tt;
        const int kb = idx_sh[t];
        atomicAdd(&ws[kb * 64 + lane], xs[t * 68 + lane]);
    }
    // one-hot encodings: rows pre-zeroed in the K-loop; write only the 1.0 entries.
    {
        if (tid < 128) {
            const int kb = idx_sh[tid];
            __builtin_nontemporal_store(1.0f, enc + (size_t)(tok0 + tid) * 1024 + kb);
        }
    }
}

// new_cs (Laplace-smoothed) + loss. 1 block x 1024.
__global__ __launch_bounds__(1024) void fin_cs(const float* __restrict__ cs_in,
                                               float* __restrict__ out,
                                               const float* __restrict__ ws) {
    __shared__ float red[16];
    __shared__ float n_sh;
    const int tid = threadIdx.x;
    const float raw = cs_in[tid] * DECAYF + ONEMF * ws[WS_COUNTS + tid];
    const float s = wave_reduce_add(raw);
    if ((tid & 63) == 0) red[tid >> 6] = s;
    __syncthreads();
    if (tid == 0) {
        float n = 0.f;
#pragma unroll
        for (int i = 0; i < 16; ++i) n += red[i];
        n_sh = n;
        out[0] = 0.25f * ws[WS_SSE] * (1.0f / 4194304.0f);  // loss
    }
    __syncthreads();
    const float n = n_sh;
    out[71368705 + tid] = (raw + EPSF) / (n + 1024.0f * EPSF) * n;
}

// new_ema_weight and new_embedding. grid 256 x 256.
__global__ __launch_bounds__(256) void fin_w(const float* __restrict__ emaw,
                                             float* __restrict__ out,
                                             const float* __restrict__ ws) {
    const int i = blockIdx.x * 256 + threadIdx.x;
    const float val = emaw[i] * DECAYF + ONEMF * ws[i];
    out[71369729 + i] = val;                               // new_ema_weight
    const float cs = out[71368705 + (i >> 6)];             // new_cs (from fin_cs)
    out[71303169 + i] = val / cs;                          // new_embedding
}

extern "C" void kernel_launch(void* const* d_in, const int* in_sizes, int n_in,
                              void* d_out, int out_size, void* d_ws, size_t ws_size,
                              hipStream_t stream) {
    const float* x    = (const float*)d_in[0];   // [16,64,64,64]
    const float* E    = (const float*)d_in[1];   // [1024,64]
    const float* cs   = (const float*)d_in[2];   // [1024]
    const float* emaw = (const float*)d_in[3];   // [1024,64]
    float* out = (float*)d_out;
    float* ws  = (float*)d_ws;

    prep_kernel<<<256, 256, 0, stream>>>(E, ws);
    vq_main<<<512, 256, 0, stream>>>(x, E, out, ws);
    fin_cs<<<1, 1024, 0, stream>>>(cs, out, ws);
    fin_w<<<256, 256, 0, stream>>>(emaw, out, ws);
}